// Round 2
// baseline (775.886 us; speedup 1.0000x reference)
//
#include <hip/hip_runtime.h>
#include <hip/hip_bf16.h>

#define E_ 160
#define CAP_ 120
#define S_ 3200
#define H_ 2048
#define I_ 192
#define K_ 6
#define MP_ 128   // padded rows per expert

typedef __attribute__((ext_vector_type(8))) short short8;
typedef __attribute__((ext_vector_type(4))) float f32x4;

__device__ __forceinline__ unsigned pack2bf(float a, float b) {
  return __builtin_amdgcn_perm(__float_as_uint(b), __float_as_uint(a), 0x07060302u);
}
__device__ __forceinline__ short f2bf1(float a) {
  return (short)(__float_as_uint(a) >> 16);
}
__device__ __forceinline__ float bf2f(short s) {
  return __uint_as_float(((unsigned)(unsigned short)s) << 16);
}
__device__ __forceinline__ int4 pack8(float4 lo, float4 hi) {
  int4 v;
  v.x = (int)pack2bf(lo.x, lo.y); v.y = (int)pack2bf(lo.z, lo.w);
  v.z = (int)pack2bf(hi.x, hi.y); v.w = (int)pack2bf(hi.z, hi.w);
  return v;
}

// ============ kernel 1: fused gather + gate/up GEMM + silu ==================
// grid: E*6. bid -> e, it (i-tile of 64), mt (m-tile of 64).
// C tile 64x128: cols 0-63 gate(i0..), 64-127 up(i0..). 4 waves 2x2,
// wave tile 32x64. BK=64, 32 K-iters, register-prefetch pipeline.
// LDS: As bf16 [64 rows][8 chunks of 8] swizzled (8KB) + Bs [128][8] (16KB).
#define NI_GU (H_ / 64)
__global__ __launch_bounds__(256) void k_gateup(
    const float* __restrict__ hidden, const int* __restrict__ tok,
    const float* __restrict__ gw, const float* __restrict__ uw,
    short* __restrict__ hb)
{
  __shared__ __align__(16) char smem[(64 * 64 + 128 * 64) * 2];  // 24576 B
  short* As = (short*)smem;
  short* Bs = As + 64 * 64;

  int bid = blockIdx.x;
  int e = bid / 6;
  int r6 = bid - e * 6;
  int it = r6 >> 1, mt = r6 & 1;
  int i0 = it * 64, m0 = mt * 64;
  int tid = threadIdx.x;
  int lane = tid & 63, w = tid >> 6;
  int wr = w >> 1, wc = w & 1;
  int lrow = lane & 15, lq = lane >> 4;

  // --- precompute staging pointers (per thread) ---
  // A: 64 rows x 8 chunks(8 fp32) = 512 chunks, 2 per thread
  const float* aptr[2]; int aphys[2];
#pragma unroll
  for (int q = 0; q < 2; ++q) {
    int c = q * 256 + tid;
    int arow = c >> 3, jc = c & 7;
    int tr_ = m0 + arow; if (tr_ > CAP_ - 1) tr_ = CAP_ - 1;  // pad rows clamp
    int tokrow = tok[e * CAP_ + tr_];
    aptr[q] = hidden + (size_t)tokrow * H_ + jc * 8;
    aphys[q] = arow * 8 + (jc ^ (arow & 7));
  }
  // B: 128 rows x 8 chunks = 1024 chunks, 4 per thread. rows 0-63 gate, 64-127 up
  const float* bptr[4]; int bphys[4];
#pragma unroll
  for (int q = 0; q < 4; ++q) {
    int c = q * 256 + tid;
    int brow = c >> 3, jc = c & 7;
    const float* base = (brow < 64)
        ? gw + ((size_t)e * I_ + i0 + brow) * H_
        : uw + ((size_t)e * I_ + i0 + brow - 64) * H_;
    bptr[q] = base + jc * 8;
    bphys[q] = brow * 8 + (jc ^ (brow & 7));
  }

  f32x4 acc[2][4] = {};
  float4 apre[2][2], bpre[4][2];

  // prologue: stage k0=0
#pragma unroll
  for (int q = 0; q < 2; ++q) {
    apre[q][0] = *(const float4*)(aptr[q]);
    apre[q][1] = *(const float4*)(aptr[q] + 4);
  }
#pragma unroll
  for (int q = 0; q < 4; ++q) {
    bpre[q][0] = *(const float4*)(bptr[q]);
    bpre[q][1] = *(const float4*)(bptr[q] + 4);
  }
#pragma unroll
  for (int q = 0; q < 2; ++q)
    *(int4*)(As + aphys[q] * 8) = pack8(apre[q][0], apre[q][1]);
#pragma unroll
  for (int q = 0; q < 4; ++q)
    *(int4*)(Bs + bphys[q] * 8) = pack8(bpre[q][0], bpre[q][1]);
  __syncthreads();

  for (int kk = 0; kk < NI_GU; ++kk) {
    bool hasNext = (kk + 1) < NI_GU;
    if (hasNext) {
      int k0 = (kk + 1) * 64;
#pragma unroll
      for (int q = 0; q < 2; ++q) {
        apre[q][0] = *(const float4*)(aptr[q] + k0);
        apre[q][1] = *(const float4*)(aptr[q] + k0 + 4);
      }
#pragma unroll
      for (int q = 0; q < 4; ++q) {
        bpre[q][0] = *(const float4*)(bptr[q] + k0);
        bpre[q][1] = *(const float4*)(bptr[q] + k0 + 4);
      }
    }
    // MFMA on current LDS tile
#pragma unroll
    for (int ks = 0; ks < 2; ++ks) {
      short8 a[2], bb[4];
#pragma unroll
      for (int tr = 0; tr < 2; ++tr) {
        int m = wr * 32 + tr * 16 + lrow;
        int jc = ks * 4 + lq;
        a[tr] = *(const short8*)(As + (m * 8 + (jc ^ (m & 7))) * 8);
      }
#pragma unroll
      for (int tc = 0; tc < 4; ++tc) {
        int n = wc * 64 + tc * 16 + lrow;
        int jc = ks * 4 + lq;
        bb[tc] = *(const short8*)(Bs + (n * 8 + (jc ^ (n & 7))) * 8);
      }
#pragma unroll
      for (int tr = 0; tr < 2; ++tr)
#pragma unroll
        for (int tc = 0; tc < 4; ++tc)
          acc[tr][tc] = __builtin_amdgcn_mfma_f32_16x16x32_bf16(
              a[tr], bb[tc], acc[tr][tc], 0, 0, 0);
    }
    __syncthreads();
    if (hasNext) {
#pragma unroll
      for (int q = 0; q < 2; ++q)
        *(int4*)(As + aphys[q] * 8) = pack8(apre[q][0], apre[q][1]);
#pragma unroll
      for (int q = 0; q < 4; ++q)
        *(int4*)(Bs + bphys[q] * 8) = pack8(bpre[q][0], bpre[q][1]);
    }
    __syncthreads();
  }

  // epilogue: wc=0 holds gate, wc=1 holds up for the same rows.
  float* exch = (float*)smem;  // [64][68] fp32 = 17408 B
  if (wc == 0) {
#pragma unroll
    for (int tr = 0; tr < 2; ++tr)
#pragma unroll
      for (int tc = 0; tc < 4; ++tc)
#pragma unroll
        for (int rg = 0; rg < 4; ++rg) {
          int row = wr * 32 + tr * 16 + lq * 4 + rg;
          int col = tc * 16 + lrow;
          exch[row * 68 + col] = acc[tr][tc][rg];
        }
  }
  __syncthreads();
  if (wc == 1) {
#pragma unroll
    for (int tr = 0; tr < 2; ++tr)
#pragma unroll
      for (int tc = 0; tc < 4; ++tc)
#pragma unroll
        for (int rg = 0; rg < 4; ++rg) {
          int row = wr * 32 + tr * 16 + lq * 4 + rg;
          int col = tc * 16 + lrow;
          float g = exch[row * 68 + col];
          float u = acc[tr][tc][rg];
          float hv = g / (1.f + __expf(-g)) * u;
          hb[((size_t)e * MP_ + m0 + row) * I_ + i0 + col] = f2bf1(hv);
        }
  }
}

// ============ kernel 2: down GEMM, o -> bf16 compact [E*120][H] =============
// grid: E*16 (expert e, 128-wide h-tile). tile 128x128, BK=64, 3 iters.
// LDS: As bf16 [128][8 chunks] swizzled (16KB) + Bs [128][8] (16KB).
__global__ __launch_bounds__(256) void k_down(
    const short* __restrict__ hb, const float* __restrict__ dw,
    short* __restrict__ ob)
{
  __shared__ __align__(16) short As[128 * 64];
  __shared__ __align__(16) short Bs[128 * 64];
  int bid = blockIdx.x;
  int e = bid >> 4, t = bid & 15;
  int n0 = t * 128;
  int tid = threadIdx.x;
  int lane = tid & 63, w = tid >> 6;
  int wr = w >> 1, wc = w & 1;
  int lrow = lane & 15, lq = lane >> 4;

  f32x4 acc[4][4] = {};

  for (int kk = 0; kk < 3; ++kk) {
    int k0 = kk * 64;
    // A: hb bf16, 128 rows x 8 chunks = 1024 chunks, 4/thread (direct copy)
#pragma unroll
    for (int q = 0; q < 4; ++q) {
      int c = q * 256 + tid;
      int arow = c >> 3, jc = c & 7;
      int4 v = *(const int4*)(hb + ((size_t)e * MP_ + arow) * I_ + k0 + jc * 8);
      *(int4*)(As + (arow * 8 + (jc ^ (arow & 7))) * 8) = v;
    }
    // B: dw fp32 -> bf16, 128 rows x 8 chunks, 4/thread
#pragma unroll
    for (int q = 0; q < 4; ++q) {
      int c = q * 256 + tid;
      int brow = c >> 3, jc = c & 7;
      const float* src = dw + ((size_t)e * H_ + n0 + brow) * I_ + k0 + jc * 8;
      float4 lo = *(const float4*)src;
      float4 hi = *(const float4*)(src + 4);
      *(int4*)(Bs + (brow * 8 + (jc ^ (brow & 7))) * 8) = pack8(lo, hi);
    }
    __syncthreads();
#pragma unroll
    for (int ks = 0; ks < 2; ++ks) {
      short8 a[4], bb[4];
#pragma unroll
      for (int tr = 0; tr < 4; ++tr) {
        int m = wr * 64 + tr * 16 + lrow;
        int jc = ks * 4 + lq;
        a[tr] = *(const short8*)(As + (m * 8 + (jc ^ (m & 7))) * 8);
      }
#pragma unroll
      for (int tc = 0; tc < 4; ++tc) {
        int n = wc * 64 + tc * 16 + lrow;
        int jc = ks * 4 + lq;
        bb[tc] = *(const short8*)(Bs + (n * 8 + (jc ^ (n & 7))) * 8);
      }
#pragma unroll
      for (int tr = 0; tr < 4; ++tr)
#pragma unroll
        for (int tc = 0; tc < 4; ++tc)
          acc[tr][tc] = __builtin_amdgcn_mfma_f32_16x16x32_bf16(
              a[tr], bb[tc], acc[tr][tc], 0, 0, 0);
    }
    __syncthreads();
  }

  // store compact rows c < 120
#pragma unroll
  for (int tr = 0; tr < 4; ++tr) {
#pragma unroll
    for (int rg = 0; rg < 4; ++rg) {
      int c = wr * 64 + tr * 16 + lq * 4 + rg;
      if (c < CAP_) {
#pragma unroll
        for (int tc = 0; tc < 4; ++tc) {
          int col = n0 + wc * 64 + tc * 16 + lrow;
          ob[((size_t)e * CAP_ + c) * H_ + col] = f2bf1(acc[tr][tc][rg]);
        }
      }
    }
  }
}

// ============ kernel 3: gather-combine ======================================
__global__ __launch_bounds__(256) void k_combine(
    const short* __restrict__ ob, const int* __restrict__ re_index,
    const float* __restrict__ topk, const float* __restrict__ shared_out,
    float* __restrict__ out)
{
  int s = blockIdx.x;
  int c0 = threadIdx.x * 8;
  const float* sh = shared_out + (size_t)s * H_ + c0;
  float4 s0 = *(const float4*)sh;
  float4 s1 = *(const float4*)(sh + 4);
  float r[8] = {s0.x, s0.y, s0.z, s0.w, s1.x, s1.y, s1.z, s1.w};
#pragma unroll
  for (int k = 0; k < K_; ++k) {
    int p = k * S_ + s;
    int idx = re_index[p];
    float wgt = topk[p];
    const short* row = ob + (size_t)idx * H_ + c0;
    short8 v = *(const short8*)row;
#pragma unroll
    for (int j = 0; j < 8; ++j) r[j] += wgt * bf2f(v[j]);
  }
  float* o = out + (size_t)s * H_ + c0;
  float4 o0, o1;
  o0.x = r[0]; o0.y = r[1]; o0.z = r[2]; o0.w = r[3];
  o1.x = r[4]; o1.y = r[5]; o1.z = r[6]; o1.w = r[7];
  *(float4*)o = o0;
  *(float4*)(o + 4) = o1;
}

extern "C" void kernel_launch(void* const* d_in, const int* in_sizes, int n_in,
                              void* d_out, int out_size, void* d_ws, size_t ws_size,
                              hipStream_t stream) {
  const float* hidden     = (const float*)d_in[0];
  const int*   tok        = (const int*)d_in[1];
  const int*   re_index   = (const int*)d_in[2];
  const float* topk       = (const float*)d_in[3];
  const float* shared_out = (const float*)d_in[4];
  const float* gw         = (const float*)d_in[5];
  const float* uw         = (const float*)d_in[6];
  const float* dw         = (const float*)d_in[7];
  float* out = (float*)d_out;

  char* ws = (char*)d_ws;
  short* hb = (short*)ws;                                   // [E][128][I] bf16, 7.9 MB
  short* ob = (short*)(ws + (size_t)E_ * MP_ * I_ * 2);     // [E*120][H] bf16, 78.6 MB

  hipLaunchKernelGGL(k_gateup,  dim3(E_ * 6),  dim3(256), 0, stream,
                     hidden, tok, gw, uw, hb);
  hipLaunchKernelGGL(k_down,    dim3(E_ * 16), dim3(256), 0, stream, hb, dw, ob);
  hipLaunchKernelGGL(k_combine, dim3(S_),      dim3(256), 0, stream,
                     ob, re_index, topk, shared_out, out);
}